// Round 7
// baseline (2535.548 us; speedup 1.0000x reference)
//
#include <hip/hip_runtime.h>
#include <cstdint>

typedef unsigned short u16;
typedef unsigned int u32;
typedef __bf16 bf16_t;
typedef bf16_t bf16x8 __attribute__((ext_vector_type(8)));
typedef float f32x4 __attribute__((ext_vector_type(4)));

#define DMODEL 4096
#define DFF 11008
#define MROWS 8192

__device__ __forceinline__ u16 f2bf(float f) {
  u32 u = __builtin_bit_cast(u32, f);
  u += 0x7FFFu + ((u >> 16) & 1u);   // RNE
  return (u16)(u >> 16);
}
__device__ __forceinline__ float bf2f(u16 h) {
  return __builtin_bit_cast(float, (u32)h << 16);
}

// async global->LDS, 16B per lane, wave-uniform LDS base + lane*16
#define GLD16(gptr, lptr)                                                  \
  __builtin_amdgcn_global_load_lds(                                        \
      (const __attribute__((address_space(1))) u32*)(gptr),                \
      (__attribute__((address_space(3))) u32*)(lptr), 16, 0, 0)

// ---------------- x -> bf16 ----------------
__global__ void k_cvt_x(const float* __restrict__ x, u16* __restrict__ xb) {
  size_t i = (size_t)blockIdx.x * blockDim.x + threadIdx.x;
  float4 v = reinterpret_cast<const float4*>(x)[i];
  ushort4 o;
  o.x = f2bf(v.x); o.y = f2bf(v.y); o.z = f2bf(v.z); o.w = f2bf(v.w);
  reinterpret_cast<ushort4*>(xb)[i] = o;
}

// ------- dequant (q - z) * s, write TRANSPOSED wT[N][K] as bf16 -------
__global__ void k_dequant_T(const int* __restrict__ q, const int* __restrict__ z,
                            const float* __restrict__ s, u16* __restrict__ wT,
                            int K, int N) {
  __shared__ u16 tile[32][36];
  const int t = threadIdx.x;
  const int n0 = blockIdx.x << 5, k0 = blockIdx.y << 5;
  {
    const int kr = t >> 3, n4 = (t & 7) << 2;
    const int k = k0 + kr, g = k >> 7;
    const int4 qv = *reinterpret_cast<const int4*>(&q[(size_t)k * N + n0 + n4]);
    const int4 zv = *reinterpret_cast<const int4*>(&z[(size_t)g * N + n0 + n4]);
    const float4 sv = *reinterpret_cast<const float4*>(&s[(size_t)g * N + n0 + n4]);
    ushort4 o;
    o.x = f2bf((float)(qv.x - zv.x) * sv.x);
    o.y = f2bf((float)(qv.y - zv.y) * sv.y);
    o.z = f2bf((float)(qv.z - zv.z) * sv.z);
    o.w = f2bf((float)(qv.w - zv.w) * sv.w);
    *reinterpret_cast<ushort4*>(&tile[kr][n4]) = o;
  }
  __syncthreads();
  {
    const int n = t >> 3, ks = (t & 7) << 2;
    ushort4 o;
    o.x = tile[ks + 0][n];
    o.y = tile[ks + 1][n];
    o.z = tile[ks + 2][n];
    o.w = tile[ks + 3][n];
    *reinterpret_cast<ushort4*>(&wT[(size_t)(n0 + n) * K + k0 + ks]) = o;
  }
}

// locality bid map: XCD owns 4 m-rows; 4 consecutive blocks share one B panel.
__device__ __forceinline__ void bid_map(int nbn, int& midx, int& nidx) {
  const int xcd = blockIdx.x & 7, lb = blockIdx.x >> 3;
  midx = xcd * 4 + (lb & 3);
  nidx = lb >> 2;
}

#define BAR asm volatile("s_barrier" ::: "memory")
#define VM4 asm volatile("s_waitcnt vmcnt(4)" ::: "memory")

// ======== fused gate+up: h = silu(x@Wg) * (x@Wu), bf16 out ========
// BM=256, BN=128, BK=64 (2 K-halves), 8 waves (2M x 4N, wave-tile 128x32).
// FULL-PHASE register prefetch: phase p+1's 12 fragment ds_reads are
// issued at the TOP of phase p's MFMA cluster (right after BAR1, pinned
// by sched_barrier(0)), so the LDS pipe drains during the ENTIRE 32-MFMA
// cluster. Old set was issued a full phase ago -> lgkm wait satisfied.
// Staging/VM4/barrier timeline identical to the enumerated-safe R6 one.
__global__ __launch_bounds__(512, 2) void k_fused(
    const u16* __restrict__ A, const u16* __restrict__ BgT,
    const u16* __restrict__ BuT, u16* __restrict__ H) {
  constexpr int Kdim = DMODEL;
  __shared__ u16 As[2][2][256 * 32];   // 64KB
  __shared__ u16 Bgs[2][2][128 * 32];  // 32KB
  __shared__ u16 Bus[2][2][128 * 32];  // 32KB

  int midx, nidx;
  bid_map(DFF / 128, midx, nidx);
  const int m0 = midx << 8;
  const int n0 = nidx << 7;
  const int t = threadIdx.x;
  const int lane = t & 63;
  const int wid = t >> 6;
  const int wr = wid >> 2, wc = wid & 3;
  const int r16 = lane & 15, quad = lane >> 4;

  const int lrow4 = lane >> 2;
  const int sslot = ((lane & 3) ^ ((lane >> 3) & 3)) << 3;  // u16 units
  const u16* Asrc = A + (size_t)(m0 + wid * 16 + lrow4) * Kdim + sslot;
  const u16* Gsrc = BgT + (size_t)(n0 + wid * 16 + lrow4) * Kdim + sslot;
  const u16* Usrc = BuT + (size_t)(n0 + wid * 16 + lrow4) * Kdim + sslot;
  const size_t rstep = (size_t)128 * Kdim;
  const int lb = wid * 512;
  constexpr int ntiles = Kdim >> 6;  // 64

#define SAF(tt, kh, bf) do {                                               \
    size_t ko = ((size_t)((tt) & (ntiles - 1)) << 6) + ((kh) << 5);        \
    GLD16(Asrc + ko,         &As[bf][kh][lb]);                             \
    GLD16(Asrc + ko + rstep, &As[bf][kh][lb + 4096]);                      \
  } while (0)
#define SGU(tt, kh, bf) do {                                               \
    size_t ko = ((size_t)((tt) & (ntiles - 1)) << 6) + ((kh) << 5);        \
    GLD16(Gsrc + ko, &Bgs[bf][kh][lb]);                                    \
    GLD16(Usrc + ko, &Bus[bf][kh][lb]);                                    \
  } while (0)

  const int fragoff = (quad ^ ((r16 >> 1) & 3)) << 3;
  const int abase = (wr * 128 + r16) * 32 + fragoff;
  const int bbase = (wc * 32 + r16) * 32 + fragoff;

  f32x4 accg[8][2], accu[8][2];
  const f32x4 zf = {0.f, 0.f, 0.f, 0.f};
#pragma unroll
  for (int mf = 0; mf < 8; ++mf)
#pragma unroll
    for (int nf = 0; nf < 2; ++nf) { accg[mf][nf] = zf; accu[mf][nf] = zf; }

  // two static fragment sets (rule #20: no runtime indexing)
  bf16x8 avA[4], av2A[4], bgA[2], buA[2];
  bf16x8 avB[4], av2B[4], bgB[2], buB[2];

#define PFF(av_, av2_, bg_, bu_, bf, kk) do {                              \
    _Pragma("unroll") for (int ii = 0; ii < 4; ++ii) {                     \
      av_[ii] = *reinterpret_cast<const bf16x8*>(                          \
          &As[bf][kk][abase + ii * 512]);                                  \
      av2_[ii] = *reinterpret_cast<const bf16x8*>(                         \
          &As[bf][kk][abase + 2048 + ii * 512]);                           \
    }                                                                      \
    _Pragma("unroll") for (int nn = 0; nn < 2; ++nn) {                     \
      bg_[nn] = *reinterpret_cast<const bf16x8*>(                          \
          &Bgs[bf][kk][bbase + nn * 512]);                                 \
      bu_[nn] = *reinterpret_cast<const bf16x8*>(                          \
          &Bus[bf][kk][bbase + nn * 512]);                                 \
    }                                                                      \
  } while (0)

  // PH: prefetch next phase's frags at cluster TOP, then 32 MFMA on cur set.
#define PHF(av_, av2_, bg_, bu_, nav_, nav2_, nbg_, nbu_, STG, VMW, bfn, kkn) \
  do {                                                                     \
    STG;                                                                   \
    VMW;                                                                   \
    BAR;                                                                   \
    PFF(nav_, nav2_, nbg_, nbu_, bfn, kkn);                                \
    __builtin_amdgcn_sched_barrier(0);                                     \
    __builtin_amdgcn_s_setprio(1);                                         \
    _Pragma("unroll") for (int ii = 0; ii < 4; ++ii)                       \
      _Pragma("unroll") for (int nn = 0; nn < 2; ++nn) {                   \
        accg[ii][nn] = __builtin_amdgcn_mfma_f32_16x16x32_bf16(            \
            av_[ii], bg_[nn], accg[ii][nn], 0, 0, 0);                      \
        accu[ii][nn] = __builtin_amdgcn_mfma_f32_16x16x32_bf16(            \
            av_[ii], bu_[nn], accu[ii][nn], 0, 0, 0);                      \
      }                                                                    \
    _Pragma("unroll") for (int ii = 0; ii < 4; ++ii)                       \
      _Pragma("unroll") for (int nn = 0; nn < 2; ++nn) {                   \
        accg[4 + ii][nn] = __builtin_amdgcn_mfma_f32_16x16x32_bf16(        \
            av2_[ii], bg_[nn], accg[4 + ii][nn], 0, 0, 0);                 \
        accu[4 + ii][nn] = __builtin_amdgcn_mfma_f32_16x16x32_bf16(        \
            av2_[ii], bu_[nn], accu[4 + ii][nn], 0, 0, 0);                 \
      }                                                                    \
    __builtin_amdgcn_s_setprio(0);                                         \
    BAR;                                                                   \
  } while (0)

  // prologue: stage regions for phases 0,1,2; confirm 0,1; prefetch ph0.
  SAF(0, 0, 0); SGU(0, 0, 0); SAF(0, 1, 0); SGU(0, 1, 0);
  SAF(1, 0, 1); SGU(1, 0, 1);
  VM4;
  BAR;
  PFF(avA, av2A, bgA, buA, 0, 0);

  constexpr int NI = ntiles >> 1;  // 32
  for (int it = 0; it < NI; ++it) {
    const int t0 = it * 2;
    PHF(avA, av2A, bgA, buA, avB, av2B, bgB, buB,
        { SAF(t0 + 1, 1, 1); SGU(t0 + 1, 1, 1); }, (void)0, 0, 1);
    PHF(avB, av2B, bgB, buB, avA, av2A, bgA, buA,
        { SAF(t0 + 2, 0, 0); SGU(t0 + 2, 0, 0); }, VM4, 1, 0);
    PHF(avA, av2A, bgA, buA, avB, av2B, bgB, buB,
        { SAF(t0 + 2, 1, 0); SGU(t0 + 2, 1, 0); }, (void)0, 1, 1);
    PHF(avB, av2B, bgB, buB, avA, av2A, bgA, buA,
        { SAF(t0 + 3, 0, 1); SGU(t0 + 3, 0, 1); }, VM4, 0, 0);
  }
  asm volatile("s_waitcnt vmcnt(0)" ::: "memory");

  // epilogue: h = silu(g) * u
  const int rb0 = m0 + wr * 128 + quad * 4;
  const int cb0 = n0 + wc * 32 + r16;
#pragma unroll
  for (int mf = 0; mf < 8; ++mf) {
#pragma unroll
    for (int nf = 0; nf < 2; ++nf) {
      f32x4 vg = accg[mf][nf];
      f32x4 vu = accu[mf][nf];
      int row = rb0 + mf * 16;
      int col = cb0 + nf * 16;
#pragma unroll
      for (int j = 0; j < 4; ++j) {
        float g = vg[j];
        float sv = g / (1.f + __expf(-g));
        H[(size_t)(row + j) * DFF + col] = f2bf(sv * vu[j]);
      }
    }
  }
#undef SAF
#undef SGU
#undef PFF
#undef PHF
}

// ======== down GEMM: out[M, DMODEL] = h @ WdT^T, f32 out ========
// Same full-phase register-prefetch transform as k_fused.
__global__ __launch_bounds__(512, 2) void k_down(
    const u16* __restrict__ A, const u16* __restrict__ BT,
    float* __restrict__ C) {
  constexpr int Ndim = DMODEL, Kdim = DFF;
  __shared__ u16 As[2][2][256 * 32];
  __shared__ u16 Bs[2][2][256 * 32];

  int midx, nidx;
  bid_map(Ndim / 256, midx, nidx);
  const int m0 = midx << 8;
  const int n0 = nidx << 8;
  const int t = threadIdx.x;
  const int lane = t & 63;
  const int wid = t >> 6;
  const int wr = wid >> 2, wc = wid & 3;
  const int r16 = lane & 15, quad = lane >> 4;

  const int lrow4 = lane >> 2;
  const int sslot = ((lane & 3) ^ ((lane >> 3) & 3)) << 3;
  const u16* Asrc = A + (size_t)(m0 + wid * 16 + lrow4) * Kdim + sslot;
  const u16* Bsrc = BT + (size_t)(n0 + wid * 16 + lrow4) * Kdim + sslot;
  const size_t rstep = (size_t)128 * Kdim;
  const int lb = wid * 512;
  constexpr int ntiles = Kdim >> 6;  // 172

#define SA(tt, kh, bf) do {                                                \
    int ttw = (tt) < ntiles ? (tt) : (tt) - ntiles;                        \
    size_t ko = ((size_t)ttw << 6) + ((kh) << 5);                          \
    GLD16(Asrc + ko,         &As[bf][kh][lb]);                             \
    GLD16(Asrc + ko + rstep, &As[bf][kh][lb + 4096]);                      \
  } while (0)
#define SB(tt, kh, bf) do {                                                \
    int ttw = (tt) < ntiles ? (tt) : (tt) - ntiles;                        \
    size_t ko = ((size_t)ttw << 6) + ((kh) << 5);                          \
    GLD16(Bsrc + ko,         &Bs[bf][kh][lb]);                             \
    GLD16(Bsrc + ko + rstep, &Bs[bf][kh][lb + 4096]);                      \
  } while (0)

  const int fragoff = (quad ^ ((r16 >> 1) & 3)) << 3;
  const int abase = (wr * 128 + r16) * 32 + fragoff;
  const int bbase = (wc * 64 + r16) * 32 + fragoff;

  f32x4 acc[8][4];
  const f32x4 zf = {0.f, 0.f, 0.f, 0.f};
#pragma unroll
  for (int mf = 0; mf < 8; ++mf)
#pragma unroll
    for (int nf = 0; nf < 4; ++nf) acc[mf][nf] = zf;

  bf16x8 avA[4], av2A[4], bvA[4];
  bf16x8 avB[4], av2B[4], bvB[4];

#define PFD(av_, av2_, bv_, bf, kk) do {                                   \
    _Pragma("unroll") for (int ii = 0; ii < 4; ++ii) {                     \
      av_[ii] = *reinterpret_cast<const bf16x8*>(                          \
          &As[bf][kk][abase + ii * 512]);                                  \
      av2_[ii] = *reinterpret_cast<const bf16x8*>(                         \
          &As[bf][kk][abase + 2048 + ii * 512]);                           \
    }                                                                      \
    _Pragma("unroll") for (int nn = 0; nn < 4; ++nn)                       \
      bv_[nn] = *reinterpret_cast<const bf16x8*>(                          \
          &Bs[bf][kk][bbase + nn * 512]);                                  \
  } while (0)

#define PHD(av_, av2_, bv_, nav_, nav2_, nbv_, STG, VMW, bfn, kkn) do {    \
    STG;                                                                   \
    VMW;                                                                   \
    BAR;                                                                   \
    PFD(nav_, nav2_, nbv_, bfn, kkn);                                      \
    __builtin_amdgcn_sched_barrier(0);                                     \
    __builtin_amdgcn_s_setprio(1);                                         \
    _Pragma("unroll") for (int ii = 0; ii < 4; ++ii)                       \
      _Pragma("unroll") for (int nn = 0; nn < 4; ++nn)                     \
        acc[ii][nn] = __builtin_amdgcn_mfma_f32_16x16x32_bf16(             \
            av_[ii], bv_[nn], acc[ii][nn], 0, 0, 0);                       \
    _Pragma("unroll") for (int ii = 0; ii < 4; ++ii)                       \
      _Pragma("unroll") for (int nn = 0; nn < 4; ++nn)                     \
        acc[4 + ii][nn] = __builtin_amdgcn_mfma_f32_16x16x32_bf16(         \
            av2_[ii], bv_[nn], acc[4 + ii][nn], 0, 0, 0);                  \
    __builtin_amdgcn_s_setprio(0);                                         \
    BAR;                                                                   \
  } while (0)

  SA(0, 0, 0); SB(0, 0, 0); SA(0, 1, 0); SB(0, 1, 0); SA(1, 0, 1); SB(1, 0, 1);
  VM4;
  BAR;
  PFD(avA, av2A, bvA, 0, 0);

  constexpr int NI = ntiles >> 1;  // 86
  for (int it = 0; it < NI; ++it) {
    const int t0 = it * 2;
    PHD(avA, av2A, bvA, avB, av2B, bvB,
        { SA(t0 + 1, 1, 1); SB(t0 + 1, 1, 1); }, (void)0, 0, 1);
    PHD(avB, av2B, bvB, avA, av2A, bvA,
        { SA(t0 + 2, 0, 0); SB(t0 + 2, 0, 0); }, VM4, 1, 0);
    PHD(avA, av2A, bvA, avB, av2B, bvB,
        { SA(t0 + 2, 1, 0); SB(t0 + 2, 1, 0); }, (void)0, 1, 1);
    PHD(avB, av2B, bvB, avA, av2A, bvA,
        { SA(t0 + 3, 0, 1); SB(t0 + 3, 0, 1); }, VM4, 0, 0);
  }
  asm volatile("s_waitcnt vmcnt(0)" ::: "memory");

  const int rb0 = m0 + wr * 128 + quad * 4;
  const int cb0 = n0 + wc * 64 + r16;
#pragma unroll
  for (int mf = 0; mf < 8; ++mf) {
#pragma unroll
    for (int nf = 0; nf < 4; ++nf) {
      f32x4 v = acc[mf][nf];
      int row = rb0 + mf * 16;
      int col = cb0 + nf * 16;
#pragma unroll
      for (int j = 0; j < 4; ++j)
        C[(size_t)(row + j) * Ndim + col] = v[j];
    }
  }
#undef SA
#undef SB
#undef PFD
#undef PHD
}

extern "C" void kernel_launch(void* const* d_in, const int* in_sizes, int n_in,
                              void* d_out, int out_size, void* d_ws, size_t ws_size,
                              hipStream_t stream) {
  const float* x  = (const float*)d_in[0];
  const int*   qg = (const int*)d_in[1];
  const int*   zg = (const int*)d_in[2];
  const float* sg = (const float*)d_in[3];
  const int*   qu = (const int*)d_in[4];
  const int*   zu = (const int*)d_in[5];
  const float* su = (const float*)d_in[6];
  const int*   qd = (const int*)d_in[7];
  const int*   zd = (const int*)d_in[8];
  const float* sd = (const float*)d_in[9];
  float* out = (float*)d_out;

  char* ws = (char*)d_ws;
  const size_t szXB = (size_t)MROWS * DMODEL * 2;
  const size_t szW  = (size_t)DMODEL * DFF * 2;
  u16* xb  = (u16*)(ws);
  u16* wgT = (u16*)(ws + szXB);
  u16* wuT = (u16*)(ws + szXB + szW);
  u16* wdT = (u16*)(ws + szXB + 2 * szW);
  u16* h   = (u16*)(ws + szXB + 3 * szW);  // [M][DFF] bf16

  k_cvt_x<<<(MROWS * DMODEL) / 1024, 256, 0, stream>>>(x, xb);
  k_dequant_T<<<dim3(DFF / 32, DMODEL / 32), 256, 0, stream>>>(qg, zg, sg, wgT, DMODEL, DFF);
  k_dequant_T<<<dim3(DFF / 32, DMODEL / 32), 256, 0, stream>>>(qu, zu, su, wuT, DMODEL, DFF);
  k_dequant_T<<<dim3(DMODEL / 32, DFF / 32), 256, 0, stream>>>(qd, zd, sd, wdT, DFF, DMODEL);

  k_fused<<<(MROWS / 256) * (DFF / 128), 512, 0, stream>>>(xb, wgT, wuT, h);
  k_down<<<(MROWS / 256) * (DMODEL / 256), 512, 0, stream>>>(h, wdT, out);
}

// Round 8
// 2312.318 us; speedup vs baseline: 1.0965x; 1.0965x over previous
//
#include <hip/hip_runtime.h>
#include <cstdint>

typedef unsigned short u16;
typedef unsigned int u32;
typedef __bf16 bf16_t;
typedef bf16_t bf16x8 __attribute__((ext_vector_type(8)));
typedef float f32x4 __attribute__((ext_vector_type(4)));

#define DMODEL 4096
#define DFF 11008
#define MROWS 8192

__device__ __forceinline__ u16 f2bf(float f) {
  u32 u = __builtin_bit_cast(u32, f);
  u += 0x7FFFu + ((u >> 16) & 1u);   // RNE
  return (u16)(u >> 16);
}
__device__ __forceinline__ float bf2f(u16 h) {
  return __builtin_bit_cast(float, (u32)h << 16);
}

// async global->LDS, 16B per lane, wave-uniform LDS base + lane*16
#define GLD16(gptr, lptr)                                                  \
  __builtin_amdgcn_global_load_lds(                                        \
      (const __attribute__((address_space(1))) u32*)(gptr),                \
      (__attribute__((address_space(3))) u32*)(lptr), 16, 0, 0)

// ---------------- x -> bf16 ----------------
__global__ void k_cvt_x(const float* __restrict__ x, u16* __restrict__ xb) {
  size_t i = (size_t)blockIdx.x * blockDim.x + threadIdx.x;
  float4 v = reinterpret_cast<const float4*>(x)[i];
  ushort4 o;
  o.x = f2bf(v.x); o.y = f2bf(v.y); o.z = f2bf(v.z); o.w = f2bf(v.w);
  reinterpret_cast<ushort4*>(xb)[i] = o;
}

// ------- dequant (q - z) * s, write TRANSPOSED wT[N][K] as bf16 -------
__global__ void k_dequant_T(const int* __restrict__ q, const int* __restrict__ z,
                            const float* __restrict__ s, u16* __restrict__ wT,
                            int K, int N) {
  __shared__ u16 tile[32][36];
  const int t = threadIdx.x;
  const int n0 = blockIdx.x << 5, k0 = blockIdx.y << 5;
  {
    const int kr = t >> 3, n4 = (t & 7) << 2;
    const int k = k0 + kr, g = k >> 7;
    const int4 qv = *reinterpret_cast<const int4*>(&q[(size_t)k * N + n0 + n4]);
    const int4 zv = *reinterpret_cast<const int4*>(&z[(size_t)g * N + n0 + n4]);
    const float4 sv = *reinterpret_cast<const float4*>(&s[(size_t)g * N + n0 + n4]);
    ushort4 o;
    o.x = f2bf((float)(qv.x - zv.x) * sv.x);
    o.y = f2bf((float)(qv.y - zv.y) * sv.y);
    o.z = f2bf((float)(qv.z - zv.z) * sv.z);
    o.w = f2bf((float)(qv.w - zv.w) * sv.w);
    *reinterpret_cast<ushort4*>(&tile[kr][n4]) = o;
  }
  __syncthreads();
  {
    const int n = t >> 3, ks = (t & 7) << 2;
    ushort4 o;
    o.x = tile[ks + 0][n];
    o.y = tile[ks + 1][n];
    o.z = tile[ks + 2][n];
    o.w = tile[ks + 3][n];
    *reinterpret_cast<ushort4*>(&wT[(size_t)(n0 + n) * K + k0 + ks]) = o;
  }
}

#define BAR asm volatile("s_barrier" ::: "memory")
#define VM4 asm volatile("s_waitcnt vmcnt(4)" ::: "memory")
#define VM6 asm volatile("s_waitcnt vmcnt(6)" ::: "memory")

// ======== fused gate+up, 2-blocks/CU: h = silu(x@Wg)*(x@Wu) ========
// BM=128, BN=128, BK=32, 4 waves (2M x 2N, 64x64/wave), 256 thr.
// Triple-buffered LDS (3 x 24KB = 72KB) -> 2 resident blocks/CU, which
// desync and overlap each other's read/MFMA phases (m114 mechanism) —
// the overlap the 1-block lockstep structure couldn't produce.
// One barrier/phase; stage-ahead=2; vmcnt(6) only (never 0 in loop).
// Per phase/wave: 12 ds_read_b128 + 6 GLD16 + 32 MFMA.
__global__ __launch_bounds__(256, 2) void k_fused128(
    const u16* __restrict__ A, const u16* __restrict__ BgT,
    const u16* __restrict__ BuT, u16* __restrict__ H) {
  constexpr int Kdim = DMODEL;
  constexpr int ntiles = Kdim >> 5;  // 128 K-steps of 32
  __shared__ u16 AsB[3 * 4096];   // 3 x [128][32] u16 = 24KB
  __shared__ u16 BgB[3 * 4096];
  __shared__ u16 BuB[3 * 4096];

  // locality map: XCD owns 8 m-blocks; 8 consecutive blocks share B panel.
  const int xcd = blockIdx.x & 7, lb = blockIdx.x >> 3;
  const int m0 = (xcd * 8 + (lb & 7)) << 7;   // 64 m-blocks
  const int n0 = (lb >> 3) << 7;              // 86 n-blocks
  const int t = threadIdx.x;
  const int lane = t & 63;
  const int wid = t >> 6;                     // 4 waves
  const int wr = wid >> 1, wc = wid & 1;      // 2M x 2N
  const int r16 = lane & 15, quad = lane >> 4;

  // staging: per region [128][32]u16, wave wid covers rows wid*32..+32 via
  // 2 GLD16 (16 rows each). lane l -> row l>>2, slot l&3; source slot
  // pre-swizzled (l&3)^((l>>3)&3) == slot ^ ((row>>1)&3).
  const int lrow = lane >> 2;
  const int sslot = ((lane & 3) ^ ((lane >> 3) & 3)) << 3;  // u16 units
  const u16* Asrc = A + (size_t)(m0 + wid * 32 + lrow) * Kdim + sslot;
  const u16* Gsrc = BgT + (size_t)(n0 + wid * 32 + lrow) * Kdim + sslot;
  const u16* Usrc = BuT + (size_t)(n0 + wid * 32 + lrow) * Kdim + sslot;
  const size_t rstep = (size_t)16 * Kdim;
  const int ldst = wid * 1024;  // u16 offset of wave chunk in a region

#define STAGE(tt, bs) do {                                                 \
    size_t ko = (size_t)((tt) & (ntiles - 1)) << 5;                        \
    GLD16(Asrc + ko,         &AsB[(bs) * 4096 + ldst]);                    \
    GLD16(Asrc + ko + rstep, &AsB[(bs) * 4096 + ldst + 512]);              \
    GLD16(Gsrc + ko,         &BgB[(bs) * 4096 + ldst]);                    \
    GLD16(Gsrc + ko + rstep, &BgB[(bs) * 4096 + ldst + 512]);              \
    GLD16(Usrc + ko,         &BuB[(bs) * 4096 + ldst]);                    \
    GLD16(Usrc + ko + rstep, &BuB[(bs) * 4096 + ldst + 512]);              \
  } while (0)

  // fragment read offsets (swizzled): slot = quad ^ ((r16>>1)&3)
  const int fragoff = (quad ^ ((r16 >> 1) & 3)) << 3;
  const int abase = (wr * 64 + r16) * 32 + fragoff;
  const int bbase = (wc * 64 + r16) * 32 + fragoff;

  f32x4 accg[4][4], accu[4][4];
  const f32x4 zf = {0.f, 0.f, 0.f, 0.f};
#pragma unroll
  for (int mi = 0; mi < 4; ++mi)
#pragma unroll
    for (int ni = 0; ni < 4; ++ni) { accg[mi][ni] = zf; accu[mi][ni] = zf; }

  // prologue: stage K-steps 0,1 into bufs 0,1; confirm step 0.
  STAGE(0, 0); STAGE(1, 1);
  VM6;

  int cur = 0;
  for (int p = 0; p < ntiles; ++p) {
    BAR;  // all waves confirmed stage(p) (their VM6 last phase) + done reading buf[(p+2)%3]
    bf16x8 av[4], bg[4], bu[4];
    const int ca = cur * 4096;
#pragma unroll
    for (int mi = 0; mi < 4; ++mi)
      av[mi] = *reinterpret_cast<const bf16x8*>(&AsB[ca + abase + mi * 512]);
#pragma unroll
    for (int ni = 0; ni < 4; ++ni) {
      bg[ni] = *reinterpret_cast<const bf16x8*>(&BgB[ca + bbase + ni * 512]);
      bu[ni] = *reinterpret_cast<const bf16x8*>(&BuB[ca + bbase + ni * 512]);
    }
    int st = cur + 2; if (st >= 3) st -= 3;
    STAGE(p + 2, st);
    VM6;  // stage(p+1) confirmed -> next phase's reads safe after next BAR
    __builtin_amdgcn_s_setprio(1);
#pragma unroll
    for (int mi = 0; mi < 4; ++mi)
#pragma unroll
      for (int ni = 0; ni < 4; ++ni) {
        accg[mi][ni] = __builtin_amdgcn_mfma_f32_16x16x32_bf16(
            av[mi], bg[ni], accg[mi][ni], 0, 0, 0);
        accu[mi][ni] = __builtin_amdgcn_mfma_f32_16x16x32_bf16(
            av[mi], bu[ni], accu[mi][ni], 0, 0, 0);
      }
    __builtin_amdgcn_s_setprio(0);
    cur += 1; if (cur >= 3) cur = 0;
  }
  asm volatile("s_waitcnt vmcnt(0)" ::: "memory");

  // epilogue: h = silu(g)*u. C/D layout: col=lane&15, row=quad*4+j.
  const int rb0 = m0 + wr * 64 + quad * 4;
  const int cb0 = n0 + wc * 64 + r16;
#pragma unroll
  for (int mi = 0; mi < 4; ++mi) {
#pragma unroll
    for (int ni = 0; ni < 4; ++ni) {
      f32x4 vg = accg[mi][ni];
      f32x4 vu = accu[mi][ni];
      int row = rb0 + mi * 16;
      int col = cb0 + ni * 16;
#pragma unroll
      for (int j = 0; j < 4; ++j) {
        float g = vg[j];
        float sv = g / (1.f + __expf(-g));
        H[(size_t)(row + j) * DFF + col] = f2bf(sv * vu[j]);
      }
    }
  }
#undef STAGE
}

// ======== down GEMM: out[M, DMODEL] = h @ WdT^T, f32 out ========
// R6 version (best measured): 256x256, 4-phase, mid-cluster prefetch.
__global__ __launch_bounds__(512, 2) void k_down(
    const u16* __restrict__ A, const u16* __restrict__ BT,
    float* __restrict__ C) {
  constexpr int Ndim = DMODEL, Kdim = DFF;
  __shared__ u16 As[2][2][256 * 32];
  __shared__ u16 Bs[2][2][256 * 32];

  const int xcd = blockIdx.x & 7, lb = blockIdx.x >> 3;
  const int m0 = (xcd * 4 + (lb & 3)) << 8;
  const int n0 = (lb >> 2) << 8;
  const int t = threadIdx.x;
  const int lane = t & 63;
  const int wid = t >> 6;
  const int wr = wid >> 2, wc = wid & 3;
  const int r16 = lane & 15, quad = lane >> 4;

  const int lrow4 = lane >> 2;
  const int sslot = ((lane & 3) ^ ((lane >> 3) & 3)) << 3;
  const u16* Asrc = A + (size_t)(m0 + wid * 16 + lrow4) * Kdim + sslot;
  const u16* Bsrc = BT + (size_t)(n0 + wid * 16 + lrow4) * Kdim + sslot;
  const size_t rstep = (size_t)128 * Kdim;
  const int lbo = wid * 512;
  constexpr int ntiles = Kdim >> 6;  // 172

#define SA(tt, kh, bf) do {                                                \
    int ttw = (tt) < ntiles ? (tt) : (tt) - ntiles;                        \
    size_t ko = ((size_t)ttw << 6) + ((kh) << 5);                          \
    GLD16(Asrc + ko,         &As[bf][kh][lbo]);                            \
    GLD16(Asrc + ko + rstep, &As[bf][kh][lbo + 4096]);                     \
  } while (0)
#define SB(tt, kh, bf) do {                                                \
    int ttw = (tt) < ntiles ? (tt) : (tt) - ntiles;                        \
    size_t ko = ((size_t)ttw << 6) + ((kh) << 5);                          \
    GLD16(Bsrc + ko,         &Bs[bf][kh][lbo]);                            \
    GLD16(Bsrc + ko + rstep, &Bs[bf][kh][lbo + 4096]);                     \
  } while (0)

  const int fragoff = (quad ^ ((r16 >> 1) & 3)) << 3;
  const int abase = (wr * 128 + r16) * 32 + fragoff;
  const int bbase = (wc * 64 + r16) * 32 + fragoff;

  f32x4 acc[8][4];
  const f32x4 zf = {0.f, 0.f, 0.f, 0.f};
#pragma unroll
  for (int mf = 0; mf < 8; ++mf)
#pragma unroll
    for (int nf = 0; nf < 4; ++nf) acc[mf][nf] = zf;

  bf16x8 avA[4], av2A[4], bvA[4];
  bf16x8 avB[4], av2B[4], bvB[4];

#define PFD(av_, av2_, bv_, bf, kk) do {                                   \
    _Pragma("unroll") for (int ii = 0; ii < 4; ++ii) {                     \
      av_[ii] = *reinterpret_cast<const bf16x8*>(                          \
          &As[bf][kk][abase + ii * 512]);                                  \
      av2_[ii] = *reinterpret_cast<const bf16x8*>(                         \
          &As[bf][kk][abase + 2048 + ii * 512]);                           \
    }                                                                      \
    _Pragma("unroll") for (int nn = 0; nn < 4; ++nn)                       \
      bv_[nn] = *reinterpret_cast<const bf16x8*>(                          \
          &Bs[bf][kk][bbase + nn * 512]);                                  \
  } while (0)

#define PHD(av_, av2_, bv_, nav_, nav2_, nbv_, STG, VMW, bfn, kkn) do {    \
    STG;                                                                   \
    VMW;                                                                   \
    BAR;                                                                   \
    __builtin_amdgcn_s_setprio(1);                                         \
    _Pragma("unroll") for (int ii = 0; ii < 4; ++ii)                       \
      _Pragma("unroll") for (int nn = 0; nn < 4; ++nn)                     \
        acc[ii][nn] = __builtin_amdgcn_mfma_f32_16x16x32_bf16(             \
            av_[ii], bv_[nn], acc[ii][nn], 0, 0, 0);                       \
    PFD(nav_, nav2_, nbv_, bfn, kkn);                                      \
    _Pragma("unroll") for (int ii = 0; ii < 4; ++ii)                       \
      _Pragma("unroll") for (int nn = 0; nn < 4; ++nn)                     \
        acc[4 + ii][nn] = __builtin_amdgcn_mfma_f32_16x16x32_bf16(         \
            av2_[ii], bv_[nn], acc[4 + ii][nn], 0, 0, 0);                  \
    __builtin_amdgcn_s_setprio(0);                                         \
    BAR;                                                                   \
  } while (0)

  SA(0, 0, 0); SB(0, 0, 0); SA(0, 1, 0); SB(0, 1, 0); SA(1, 0, 1); SB(1, 0, 1);
  VM4;
  BAR;
  PFD(avA, av2A, bvA, 0, 0);

  constexpr int NI = ntiles >> 1;  // 86
  for (int it = 0; it < NI; ++it) {
    const int t0 = it * 2;
    PHD(avA, av2A, bvA, avB, av2B, bvB,
        { SA(t0 + 1, 1, 1); SB(t0 + 1, 1, 1); }, (void)0, 0, 1);
    PHD(avB, av2B, bvB, avA, av2A, bvA,
        { SA(t0 + 2, 0, 0); SB(t0 + 2, 0, 0); }, VM4, 1, 0);
    PHD(avA, av2A, bvA, avB, av2B, bvB,
        { SA(t0 + 2, 1, 0); SB(t0 + 2, 1, 0); }, (void)0, 1, 1);
    PHD(avB, av2B, bvB, avA, av2A, bvA,
        { SA(t0 + 3, 0, 1); SB(t0 + 3, 0, 1); }, VM4, 0, 0);
  }
  asm volatile("s_waitcnt vmcnt(0)" ::: "memory");

  const int rb0 = m0 + wr * 128 + quad * 4;
  const int cb0 = n0 + wc * 64 + r16;
#pragma unroll
  for (int mf = 0; mf < 8; ++mf) {
#pragma unroll
    for (int nf = 0; nf < 4; ++nf) {
      f32x4 v = acc[mf][nf];
      int row = rb0 + mf * 16;
      int col = cb0 + nf * 16;
#pragma unroll
      for (int j = 0; j < 4; ++j)
        C[(size_t)(row + j) * Ndim + col] = v[j];
    }
  }
#undef SA
#undef SB
#undef PFD
#undef PHD
}

extern "C" void kernel_launch(void* const* d_in, const int* in_sizes, int n_in,
                              void* d_out, int out_size, void* d_ws, size_t ws_size,
                              hipStream_t stream) {
  const float* x  = (const float*)d_in[0];
  const int*   qg = (const int*)d_in[1];
  const int*   zg = (const int*)d_in[2];
  const float* sg = (const float*)d_in[3];
  const int*   qu = (const int*)d_in[4];
  const int*   zu = (const int*)d_in[5];
  const float* su = (const float*)d_in[6];
  const int*   qd = (const int*)d_in[7];
  const int*   zd = (const int*)d_in[8];
  const float* sd = (const float*)d_in[9];
  float* out = (float*)d_out;

  char* ws = (char*)d_ws;
  const size_t szXB = (size_t)MROWS * DMODEL * 2;
  const size_t szW  = (size_t)DMODEL * DFF * 2;
  u16* xb  = (u16*)(ws);
  u16* wgT = (u16*)(ws + szXB);
  u16* wuT = (u16*)(ws + szXB + szW);
  u16* wdT = (u16*)(ws + szXB + 2 * szW);
  u16* h   = (u16*)(ws + szXB + 3 * szW);  // [M][DFF] bf16

  k_cvt_x<<<(MROWS * DMODEL) / 1024, 256, 0, stream>>>(x, xb);
  k_dequant_T<<<dim3(DFF / 32, DMODEL / 32), 256, 0, stream>>>(qg, zg, sg, wgT, DMODEL, DFF);
  k_dequant_T<<<dim3(DFF / 32, DMODEL / 32), 256, 0, stream>>>(qu, zu, su, wuT, DMODEL, DFF);
  k_dequant_T<<<dim3(DMODEL / 32, DFF / 32), 256, 0, stream>>>(qd, zd, sd, wdT, DFF, DMODEL);

  // h = silu(x@Wg)*(x@Wu): 64 m-blocks x 86 n-blocks, 256 thr, 2 blocks/CU
  k_fused128<<<(MROWS / 128) * (DFF / 128), 256, 0, stream>>>(xb, wgT, wuT, h);
  // out = h @ Wd
  k_down<<<(MROWS / 256) * (DMODEL / 256), 512, 0, stream>>>(h, wdT, out);
}